// Round 5
// baseline (211.139 us; speedup 1.0000x reference)
//
#include <hip/hip_runtime.h>
#include <hip/hip_cooperative_groups.h>
#include <math.h>

namespace cg = cooperative_groups;

#define MARGIN 1.0f

typedef short short8 __attribute__((ext_vector_type(8)));
typedef unsigned short ushort8 __attribute__((ext_vector_type(8)));
typedef float floatx16 __attribute__((ext_vector_type(16)));

__device__ inline unsigned short bf16_rne(float x) {
  unsigned u = __float_as_uint(x);
  unsigned r = (u + 0x7FFF + ((u >> 16) & 1)) >> 16;
  return (unsigned short)r;
}
__device__ inline float bf16_to_f32(unsigned short h) {
  return __uint_as_float(((unsigned)h) << 16);
}

// Single cooperative mega-kernel: conv -> dist -> anchor loss -> total.
// Grid MUST be 256 blocks x 256 threads (N=1024, D=512 assumed, as prior rounds).
// 64 KB LDS -> 2 blocks/CU -> 256 blocks co-resident under cooperative launch.
__global__ __launch_bounds__(256, 2) void mega_kernel(
    const float* __restrict__ f, const int* __restrict__ labels,
    unsigned short* __restrict__ fhi, unsigned short* __restrict__ flo,
    float* __restrict__ sq, float* dist, float* gacc, int* ticket,
    float* __restrict__ out, int N, int D) {
  // 64 KB: phase 1 uses it as chunked MFMA tiles; phase 2 reuses as per-wave
  // pos/neg compaction buffers.
  __shared__ ushort8 T[2][4][8][64];

  cg::grid_group grid = cg::this_grid();
  const int tid = threadIdx.x;
  const int bid = blockIdx.x;
  const int lane = tid & 63;
  const int w = tid >> 6;          // wave 0..3

  // ================= Phase 0: fp32 -> bf16 hi/lo (chunked) + sq =============
  {
    if (bid == 0 && tid == 0) { *gacc = 0.f; *ticket = 0; }
    const int row = bid * 4 + w;       // 256 blocks * 4 rows = 1024
    const int c = lane;                // k-chunk 0..63 (D=512)
    float a = 0.f;
    if (c * 8 < D) {
      const float* src = f + (size_t)row * D + c * 8;
      float4 v0 = *(const float4*)(src);
      float4 v1 = *(const float4*)(src + 4);
      float xs[8] = {v0.x, v0.y, v0.z, v0.w, v1.x, v1.y, v1.z, v1.w};
      ushort8 hs, ls;
#pragma unroll
      for (int e = 0; e < 8; ++e) {
        float x = xs[e];
        a += x * x;
        unsigned short hh = bf16_rne(x);
        hs[e] = hh;
        ls[e] = bf16_rne(x - bf16_to_f32(hh));
      }
      const size_t off = ((size_t)c * N + row) * 8;   // chunked [chunk][row][8]
      *(ushort8*)(fhi + off) = hs;
      *(ushort8*)(flo + off) = ls;
    }
    for (int o = 32; o > 0; o >>= 1) a += __shfl_down(a, o, 64);
    if (lane == 0) sq[row] = a;
  }
  __threadfence();
  grid.sync();

  // ================= Phase 1: distance tile via bf16 MFMA hi/lo =============
  {
    const int by = bid >> 4, bx = bid & 15;
    const int rowBase = by * 64, colBase = bx * 64;
    const unsigned short* srcs[4] = {fhi, flo, fhi, flo};
    const int bases[4] = {rowBase, rowBase, colBase, colBase};
    const int wr = (w >> 1) * 32;
    const int wc = (w & 1) * 32;
    const int m = lane & 31;
    const int h = lane >> 5;

    ushort8 regs[8];
    auto loadRegs = [&](int k0) {
      const int c0 = k0 >> 3;
#pragma unroll
      for (int s = 0; s < 8; ++s) {
        const int a = s >> 1;
        const int c = (w << 1) | (s & 1);
        regs[s] = *(const ushort8*)(srcs[a] + ((size_t)(c0 + c) * N + bases[a] + lane) * 8);
      }
    };
    auto storeRegs = [&](int b) {
#pragma unroll
      for (int s = 0; s < 8; ++s) {
        const int a = s >> 1;
        const int c = (w << 1) | (s & 1);
        T[b][a][c][lane] = regs[s];   // lane-sequential 16B, conflict-free
      }
    };

    floatx16 acc = {};
    int b = 0;
    loadRegs(0);
    storeRegs(0);
    for (int k0 = 0; k0 < D; k0 += 64) {
      if (k0 + 64 < D) loadRegs(k0 + 64);
      __syncthreads();
#pragma unroll
      for (int kk = 0; kk < 4; ++kk) {
        const int c = 2 * kk + h;
        short8 ahf = *(const short8*)&T[b][0][c][wr + m];
        short8 alf = *(const short8*)&T[b][1][c][wr + m];
        short8 bhf = *(const short8*)&T[b][2][c][wc + m];
        short8 blf = *(const short8*)&T[b][3][c][wc + m];
        acc = __builtin_amdgcn_mfma_f32_32x32x16_bf16(ahf, bhf, acc, 0, 0, 0);
        acc = __builtin_amdgcn_mfma_f32_32x32x16_bf16(ahf, blf, acc, 0, 0, 0);
        acc = __builtin_amdgcn_mfma_f32_32x32x16_bf16(alf, bhf, acc, 0, 0, 0);
      }
      if (k0 + 64 < D) storeRegs(b ^ 1);
      b ^= 1;
    }

    // Epilogue: C/D layout col=lane&31, row=(reg&3)+8*(reg>>2)+4*(lane>>5)
    const int col = colBase + wc + m;
    const float sqc = sq[col];
#pragma unroll
    for (int r = 0; r < 16; ++r) {
      const int row = rowBase + wr + (r & 3) + 8 * (r >> 2) + 4 * h;
      float d2 = sq[row] + sqc - 2.0f * acc[r];
      d2 = d2 > 0.f ? d2 : 0.f;
      dist[(size_t)row * N + col] = sqrtf(d2);
    }
  }
  __threadfence();
  grid.sync();

  // ================= Phase 2: per-anchor loss, one WAVE per anchor ==========
  {
    __syncthreads();   // all waves done with phase-1 T reads before reuse
    float* buf = ((float*)T) + w * 1056;  // per-wave private 1024 + pad
    const int i = bid * 4 + w;            // anchor
    const int lab = labels[i];
    const float* drow = dist + (size_t)i * N;

    // Compaction: pos from front, neg from back. Counters are wave-uniform.
    int cp = 0, cn = 0;
    for (int it = 0; it < 16; ++it) {     // 16*64 = 1024 = N
      int j = it * 64 + lane;
      float d = drow[j];
      bool isPos = (labels[j] == lab);
      unsigned long long mp = __ballot(isPos);
      unsigned long long lt = (1ull << lane) - 1ull;
      int pp = __popcll(mp & lt);
      if (isPos) buf[cp + pp] = d;
      else       buf[1023 - cn - (lane - pp)] = d;
      int npos = __popcll(mp);
      cp += npos;
      cn += 64 - npos;
    }
    __syncthreads();

    const int np = cp, nn = cn;
    float dk[16];
#pragma unroll
    for (int e = 0; e < 16; ++e) {
      int k = e * 64 + lane;
      dk[e] = (k < nn) ? buf[1023 - k] : 1e30f;   // pad -> relu 0
    }

    float accv = 0.f;
    for (int p = 0; p < np; ++p) {
      float t = buf[p] + MARGIN;          // broadcast LDS read
#pragma unroll
      for (int e = 0; e < 16; ++e) {
        float v = t - dk[e];
        accv += (v > 0.f) ? v : 0.f;
      }
    }

    for (int o = 32; o > 0; o >>= 1) accv += __shfl_down(accv, o, 64);
    float* red = ((float*)T) + 4 * 1056;
    if (lane == 0) red[w] = accv;
    __syncthreads();
    if (tid == 0) {
      float bsum = red[0] + red[1] + red[2] + red[3];
      atomicAdd(gacc, bsum);
      __threadfence();
      int old = atomicAdd(ticket, 1);
      if (old == (int)gridDim.x - 1) {
        float total = atomicAdd(gacc, 0.0f);   // atomic read of final sum
        out[0] = (float)((double)total / ((double)N + 1e-8));
      }
    }
  }
}

extern "C" void kernel_launch(void* const* d_in, const int* in_sizes, int n_in,
                              void* d_out, int out_size, void* d_ws, size_t ws_size,
                              hipStream_t stream) {
  const float* f = (const float*)d_in[0];
  const int* labels = (const int*)d_in[1];
  int N = in_sizes[1];           // 1024
  int D = in_sizes[0] / N;       // 512
  float* out = (float*)d_out;

  // ws layout: fhi [N*D u16 chunked] | flo [N*D u16 chunked] | sq [N f32]
  //          | dist [N*N f32] | gacc [f32] | ticket [i32]
  unsigned short* fhi = (unsigned short*)d_ws;
  unsigned short* flo = fhi + (size_t)N * D;
  float* sq = (float*)(flo + (size_t)N * D);
  float* dist = sq + N;
  float* gacc = dist + (size_t)N * N;
  int* ticket = (int*)(gacc + 1);

  void* args[] = {&f, &labels, &fhi, &flo, &sq, &dist, &gacc, &ticket, &out, &N, &D};
  hipLaunchCooperativeKernel((void*)mega_kernel, dim3(256), dim3(256), args, 0, stream);
}

// Round 9
// 83.124 us; speedup vs baseline: 2.5400x; 2.5400x over previous
//
#include <hip/hip_runtime.h>
#include <math.h>

#define MARGIN 1.0f

typedef short short8 __attribute__((ext_vector_type(8)));
typedef unsigned short ushort8 __attribute__((ext_vector_type(8)));
typedef float floatx16 __attribute__((ext_vector_type(16)));

__device__ inline unsigned short bf16_rne(float x) {
  unsigned u = __float_as_uint(x);
  unsigned r = (u + 0x7FFF + ((u >> 16) & 1)) >> 16;
  return (unsigned short)r;
}
__device__ inline float bf16_to_f32(unsigned short h) {
  return __uint_as_float(((unsigned)h) << 16);
}

// ---------------- Kernel 1: fused conv + distance matrix (bf16 MFMA hi/lo) --
// 64x64 tile per block, 256 threads = 4 waves. Each block loads its fp32
// sub-tiles (coalesced float4), converts to bf16 hi/lo in registers, stores
// into chunked conflict-free LDS, runs 3x mfma_32x32x16_bf16 per K16-step.
// Row/col squared norms computed exactly from the same fp32 loads.
// Double-buffered LDS, one barrier per K-iteration, register prefetch.
__global__ __launch_bounds__(256) void dist_fused_kernel(
    const float* __restrict__ f, float* __restrict__ dist, int N, int D) {
  // [2 bufs][4 arrays: Ah,Al,Bh,Bl][8 chunks][64 rows] of ushort8 = 64 KB
  __shared__ ushort8 T[2][4][8][64];

  const int tid = threadIdx.x;
  const int w = tid >> 6;          // wave 0..3
  const int lane = tid & 63;
  const int rowBase = blockIdx.y * 64;
  const int colBase = blockIdx.x * 64;

  // staging mapping: row r = tid&63, k-quarter q = tid>>6 (16 floats each)
  const int sr = tid & 63;
  const int q = tid >> 6;

  // compute mapping: wave w -> 32x32 tile at (wr, wc)
  const int wr = (w >> 1) * 32;
  const int wc = (w & 1) * 32;
  const int m = lane & 31;
  const int h = lane >> 5;         // k-half selector

  float aF[16], bF[16];
  float asq_part = 0.f, bsq_part = 0.f;

  auto loadF = [&](int k0) {
    const float* pa = f + (size_t)(rowBase + sr) * D + k0 + q * 16;
    const float* pb = f + (size_t)(colBase + sr) * D + k0 + q * 16;
#pragma unroll
    for (int v = 0; v < 4; ++v) {
      *(float4*)&aF[4 * v] = *(const float4*)(pa + 4 * v);
      *(float4*)&bF[4 * v] = *(const float4*)(pb + 4 * v);
    }
  };
  auto convStore = [&](int b) {
#pragma unroll
    for (int half = 0; half < 2; ++half) {
      ushort8 ah, al, bh, bl;
#pragma unroll
      for (int e = 0; e < 8; ++e) {
        float xa = aF[half * 8 + e];
        float xb = bF[half * 8 + e];
        asq_part += xa * xa;
        bsq_part += xb * xb;
        unsigned short hA = bf16_rne(xa);
        unsigned short hB = bf16_rne(xb);
        ah[e] = hA; al[e] = bf16_rne(xa - bf16_to_f32(hA));
        bh[e] = hB; bl[e] = bf16_rne(xb - bf16_to_f32(hB));
      }
      const int c = 2 * q + half;
      T[b][0][c][sr] = ah;   // lane-sequential 16B -> conflict-free
      T[b][1][c][sr] = al;
      T[b][2][c][sr] = bh;
      T[b][3][c][sr] = bl;
    }
  };

  floatx16 acc = {};
  int b = 0;

  loadF(0);
  convStore(0);

  for (int k0 = 0; k0 < D; k0 += 64) {
    if (k0 + 64 < D) loadF(k0 + 64);   // prefetch next fp32 window
    __syncthreads();                   // buffer b filled; prev reads done
#pragma unroll
    for (int kk = 0; kk < 4; ++kk) {
      const int c = 2 * kk + h;
      short8 ahf = *(const short8*)&T[b][0][c][wr + m];
      short8 alf = *(const short8*)&T[b][1][c][wr + m];
      short8 bhf = *(const short8*)&T[b][2][c][wc + m];
      short8 blf = *(const short8*)&T[b][3][c][wc + m];
      acc = __builtin_amdgcn_mfma_f32_32x32x16_bf16(ahf, bhf, acc, 0, 0, 0);
      acc = __builtin_amdgcn_mfma_f32_32x32x16_bf16(ahf, blf, acc, 0, 0, 0);
      acc = __builtin_amdgcn_mfma_f32_32x32x16_bf16(alf, bhf, acc, 0, 0, 0);
    }
    if (k0 + 64 < D) convStore(b ^ 1); // convert+fill other buffer
    b ^= 1;
  }

  // Cross-wave reduce of per-thread sq partials via LDS overlay on T.
  __syncthreads();                     // all frag reads done; T reusable
  float* sqbuf = (float*)T;            // [2][4][64]: {A,B} x quarter x row
  sqbuf[q * 64 + sr] = asq_part;
  sqbuf[256 + q * 64 + sr] = bsq_part;
  __syncthreads();

  // Epilogue: C/D layout col=lane&31, row=(reg&3)+8*(reg>>2)+4*(lane>>5)
  const int colL = wc + m;
  const float sqc = sqbuf[256 + colL] + sqbuf[320 + colL] + sqbuf[384 + colL] + sqbuf[448 + colL];
  const int col = colBase + colL;
#pragma unroll
  for (int r = 0; r < 16; ++r) {
    const int rowL = wr + (r & 3) + 8 * (r >> 2) + 4 * h;
    const float sqr = sqbuf[rowL] + sqbuf[64 + rowL] + sqbuf[128 + rowL] + sqbuf[192 + rowL];
    float d2 = sqr + sqc - 2.0f * acc[r];
    d2 = d2 > 0.f ? d2 : 0.f;
    dist[(size_t)(rowBase + rowL) * N + col] = sqrtf(d2);
  }
}

// ---------------- Kernel 2: per-anchor triplet loss (ballot compaction) ----
__global__ __launch_bounds__(256) void anchor_loss_kernel(
    const float* __restrict__ dist, const int* __restrict__ labels,
    float* __restrict__ partial, int N) {
  const int i = blockIdx.x;
  const int tid = threadIdx.x;
  const int lane = tid & 63;

  __shared__ float dpos[1024];   // stored as d + MARGIN
  __shared__ float dneg[1024];
  __shared__ int cnt[2];
  __shared__ float red[4];

  if (tid < 2) cnt[tid] = 0;
  __syncthreads();

  const int lab = labels[i];
  const float* drow = dist + (size_t)i * N;

  for (int jb = 0; jb < N; jb += 256) {
    int j = jb + tid;
    float d = drow[j];
    bool isPos = (labels[j] == lab);

    unsigned long long mp = __ballot(isPos);
    unsigned long long mn = ~mp;   // all 64 lanes valid (N % 256 == 0)
    unsigned long long lt = (1ull << lane) - 1ull;

    int base_p = 0, base_n = 0;
    if (lane == 0) {
      base_p = atomicAdd(&cnt[0], __popcll(mp));
      base_n = atomicAdd(&cnt[1], 64 - __popcll(mp));
    }
    base_p = __shfl(base_p, 0, 64);
    base_n = __shfl(base_n, 0, 64);

    if (isPos) dpos[base_p + __popcll(mp & lt)] = d + MARGIN;
    else       dneg[base_n + __popcll(mn & lt)] = d;
  }
  __syncthreads();

  const int np = cnt[0], nn = cnt[1];

  float dk[4];
#pragma unroll
  for (int e = 0; e < 4; ++e) {
    int k = tid + 256 * e;
    dk[e] = (k < nn) ? dneg[k] : 1e30f;   // pad -> relu term 0
  }

  float accv = 0.f;
  for (int p = 0; p < np; ++p) {
    float t = dpos[p];                    // broadcast LDS read
#pragma unroll
    for (int e = 0; e < 4; ++e) {
      float v = t - dk[e];
      accv += (v > 0.f) ? v : 0.f;
    }
  }

  for (int off = 32; off > 0; off >>= 1) accv += __shfl_down(accv, off, 64);
  if (lane == 0) red[tid >> 6] = accv;
  __syncthreads();
  if (tid == 0) partial[i] = red[0] + red[1] + red[2] + red[3];
}

// ---------------- Kernel 3: final reduction ----------------
__global__ __launch_bounds__(256) void final_reduce_kernel(
    const float* __restrict__ partial, float* __restrict__ out, int N) {
  float acc = 0.f;
  for (int j = threadIdx.x; j < N; j += 256) acc += partial[j];
  for (int off = 32; off > 0; off >>= 1) acc += __shfl_down(acc, off, 64);
  __shared__ float red[4];
  if ((threadIdx.x & 63) == 0) red[threadIdx.x >> 6] = acc;
  __syncthreads();
  if (threadIdx.x == 0) {
    double s = (double)red[0] + (double)red[1] + (double)red[2] + (double)red[3];
    out[0] = (float)(s / ((double)N + 1e-8));
  }
}

extern "C" void kernel_launch(void* const* d_in, const int* in_sizes, int n_in,
                              void* d_out, int out_size, void* d_ws, size_t ws_size,
                              hipStream_t stream) {
  const float* f = (const float*)d_in[0];
  const int* labels = (const int*)d_in[1];
  int N = in_sizes[1];           // 1024
  int D = in_sizes[0] / N;       // 512
  float* out = (float*)d_out;

  // ws layout: dist [N*N f32] | partial [N f32]
  float* dist = (float*)d_ws;
  float* partial = dist + (size_t)N * N;

  dim3 grid(N / 64, N / 64);
  dist_fused_kernel<<<grid, 256, 0, stream>>>(f, dist, N, D);
  anchor_loss_kernel<<<N, 256, 0, stream>>>(dist, labels, partial, N);
  final_reduce_kernel<<<1, 256, 0, stream>>>(partial, out, N);
}